// Round 1
// baseline (2192.454 us; speedup 1.0000x reference)
//
#include <hip/hip_runtime.h>
#include <math.h>

#define C_DIM 4224
#define HW_PIX 50176          // 224*224
#define NSEG 100

// ---- workspace layout (float offsets) ----
#define FEATT_LD    128
#define OFF_FEATT   0                          // [4224][128], cols >=100 stay zero
#define SZ_FEATT    (C_DIM * FEATT_LD)         // 540672
#define OFF_CNT     (OFF_FEATT + SZ_FEATT)     // 540672
#define OFF_LCNT    (OFF_CNT + 128)            // 540800  (100*3 used)
#define OFF_NORMSQ  (OFF_LCNT + 384)           // 541184
#define OFF_LABELS  (OFF_NORMSQ + 128)         // 541312  (int storage)
#define OFF_RNORM   (OFF_LABELS + 128)         // 541440
#define OFF_H1      (OFF_RNORM + 128)          // 541568  [128][1024]
#define OFF_H2      (OFF_H1 + 128 * 1024)      // 672640  [128][1024]
#define WS_FLOATS   (OFF_H2 + 128 * 1024)      // 803712 floats = 3.07 MB

__global__ __launch_bounds__(256) void k_zero(float4* p, int n4) {
    int i = blockIdx.x * blockDim.x + threadIdx.x;
    int stride = gridDim.x * blockDim.x;
    float4 z = make_float4(0.f, 0.f, 0.f, 0.f);
    for (; i < n4; i += stride) p[i] = z;
}

// cnt[s], lcnt[s][3] from sp, y
__global__ __launch_bounds__(256) void k_meta(const int* __restrict__ sp,
                                              const int* __restrict__ y,
                                              float* cnt, float* lcnt) {
    __shared__ float sc[NSEG];
    __shared__ float sl[NSEG * 3];
    int t = threadIdx.x;
    for (int i = t; i < NSEG; i += 256) sc[i] = 0.f;
    for (int i = t; i < NSEG * 3; i += 256) sl[i] = 0.f;
    __syncthreads();
    for (int p = blockIdx.x * 256 + t; p < HW_PIX; p += gridDim.x * 256) {
        int s = sp[p];
        int lab = y[p];
        atomicAdd(&sc[s], 1.f);
        atomicAdd(&sl[s * 3 + lab], 1.f);
    }
    __syncthreads();
    for (int i = t; i < NSEG; i += 256) if (sc[i] != 0.f) atomicAdd(&cnt[i], sc[i]);
    for (int i = t; i < NSEG * 3; i += 256) if (sl[i] != 0.f) atomicAdd(&lcnt[i], sl[i]);
}

// one block per channel c: featT[c][s] = (sum of feat_map[c][p] where sp[p]==s) / max(cnt,1)
__global__ __launch_bounds__(256) void k_segsum(const float* __restrict__ fm,
                                                const int* __restrict__ sp,
                                                const float* __restrict__ cnt,
                                                float* __restrict__ featT,
                                                float* __restrict__ normsq) {
    int c = blockIdx.x;
    __shared__ float bins[NSEG];
    int t = threadIdx.x;
    if (t < NSEG) bins[t] = 0.f;
    __syncthreads();
    const float4* row = (const float4*)(fm + (size_t)c * HW_PIX);
    const int4* spv = (const int4*)sp;
    // HW_PIX/4 = 12544 = 49 * 256 exactly
    for (int i = t; i < HW_PIX / 4; i += 256) {
        float4 v = row[i];
        int4 s = spv[i];
        atomicAdd(&bins[s.x], v.x);
        atomicAdd(&bins[s.y], v.y);
        atomicAdd(&bins[s.z], v.z);
        atomicAdd(&bins[s.w], v.w);
    }
    __syncthreads();
    if (t < NSEG) {
        float cn = cnt[t];
        float v = bins[t] / fmaxf(cn, 1.f);
        featT[(size_t)c * FEATT_LD + t] = v;
        atomicAdd(&normsq[t], v * v);
    }
}

__global__ __launch_bounds__(128) void k_labels(const float* cnt, const float* lcnt,
                                                const float* normsq, int* labels,
                                                float* rnorm) {
    int s = threadIdx.x;
    if (s < NSEG) {
        float l0 = lcnt[s * 3 + 0], l1 = lcnt[s * 3 + 1], l2 = lcnt[s * 3 + 2];
        int lab = 0;
        float best = l0;
        if (l1 > best) { best = l1; lab = 1; }
        if (l2 > best) { lab = 2; }
        float cn = cnt[s];
        int ovr = (l2 > floorf(cn * 0.5f)) ? 2 : ((l1 >= 1.f) ? 1 : 0);
        labels[s] = (lab == 0) ? ovr : lab;
        rnorm[s] = 1.f / sqrtf(normsq[s]);
    }
}

// block i: best/argmax over labeled columns j of aff[i][j]; write prop_labels
__global__ __launch_bounds__(128) void k_prop(const float* __restrict__ featT,
                                              const int* __restrict__ labels,
                                              const float* __restrict__ rnorm,
                                              float* __restrict__ out) {
    int i = blockIdx.x;
    int j = threadIdx.x;
    float val = -INFINITY;
    if (j < NSEG && labels[j] != 0) {
        float a0 = 0.f, a1 = 0.f, a2 = 0.f, a3 = 0.f;
        const float* ft = featT;
        for (int k = 0; k < C_DIM; k += 4) {
            a0 = fmaf(ft[(size_t)(k + 0) * FEATT_LD + i], ft[(size_t)(k + 0) * FEATT_LD + j], a0);
            a1 = fmaf(ft[(size_t)(k + 1) * FEATT_LD + i], ft[(size_t)(k + 1) * FEATT_LD + j], a1);
            a2 = fmaf(ft[(size_t)(k + 2) * FEATT_LD + i], ft[(size_t)(k + 2) * FEATT_LD + j], a2);
            a3 = fmaf(ft[(size_t)(k + 3) * FEATT_LD + i], ft[(size_t)(k + 3) * FEATT_LD + j], a3);
        }
        val = ((a0 + a1) + (a2 + a3)) * rnorm[i] * rnorm[j];
    }
    __shared__ float sv[128];
    __shared__ int si[128];
    sv[j] = val;
    si[j] = j;
    __syncthreads();
    for (int off = 64; off > 0; off >>= 1) {
        if (j < off) {
            float v2 = sv[j + off];
            int i2 = si[j + off];
            if (v2 > sv[j] || (v2 == sv[j] && i2 < si[j])) { sv[j] = v2; si[j] = i2; }
        }
        __syncthreads();
    }
    if (j == 0) {
        int li = labels[i];
        int prop = (li == 0 && sv[0] >= 0.8f) ? labels[si[0]] : li;
        out[300 + i] = (float)prop;
    }
}

// C(128 x N) += op(A)(128 x K) @ B(K x N); op = optional relu(x + abias[k])
// transA=1: A is featT-style K-major with leading dim lda (element (m,k) at A[k*lda+m])
// grid: x = N/64, y = 2 (m tiles of 64), z = ksplit; Kt = K/ksplit (multiple of 32)
__global__ __launch_bounds__(256) void k_gemm(const float* __restrict__ A, int lda, int transA,
                                              const float* __restrict__ abias,
                                              const float* __restrict__ B, int ldb,
                                              float* __restrict__ Cout, int ldc, int Kt) {
    __shared__ float As[32][68];
    int t = threadIdx.x;
    int tx = t & 15, ty = t >> 4;
    int n0 = blockIdx.x * 64;
    int m0 = blockIdx.y * 64;
    int k0 = blockIdx.z * Kt;
    float acc[4][4] = {};
    for (int ks = 0; ks < Kt; ks += 32) {
        __syncthreads();
        if (transA) {
            // 32 kk x 16 m-float4
            for (int idx = t; idx < 512; idx += 256) {
                int kk = idx >> 4, mq = idx & 15;
                int gk = k0 + ks + kk;
                float4 v = *(const float4*)(A + (size_t)gk * lda + m0 + mq * 4);
                *(float4*)&As[kk][mq * 4] = v;
            }
        } else {
            // 64 m x 8 k-float4, transpose-scatter
            for (int idx = t; idx < 512; idx += 256) {
                int m = idx >> 3, kq = idx & 7;
                int gk = k0 + ks + kq * 4;
                float4 v = *(const float4*)(A + (size_t)(m0 + m) * lda + gk);
                if (abias) {
                    float4 b = *(const float4*)(abias + gk);
                    v.x = fmaxf(v.x + b.x, 0.f);
                    v.y = fmaxf(v.y + b.y, 0.f);
                    v.z = fmaxf(v.z + b.z, 0.f);
                    v.w = fmaxf(v.w + b.w, 0.f);
                }
                As[kq * 4 + 0][m] = v.x;
                As[kq * 4 + 1][m] = v.y;
                As[kq * 4 + 2][m] = v.z;
                As[kq * 4 + 3][m] = v.w;
            }
        }
        __syncthreads();
        const float* Bp = B + (size_t)(k0 + ks) * ldb + n0 + (tx << 2);
#pragma unroll
        for (int kk = 0; kk < 32; kk++) {
            float4 w = *(const float4*)(Bp + (size_t)kk * ldb);
            float4 a = *(const float4*)&As[kk][ty << 2];
            float av[4] = {a.x, a.y, a.z, a.w};
            float wv[4] = {w.x, w.y, w.z, w.w};
#pragma unroll
            for (int i = 0; i < 4; i++)
#pragma unroll
                for (int j = 0; j < 4; j++)
                    acc[i][j] = fmaf(av[i], wv[j], acc[i][j]);
        }
    }
#pragma unroll
    for (int i = 0; i < 4; i++) {
        int m = m0 + (ty << 2) + i;
#pragma unroll
        for (int j = 0; j < 4; j++)
            atomicAdd(&Cout[(size_t)m * ldc + n0 + (tx << 2) + j], acc[i][j]);
    }
}

// block m: h3 = relu(relu(h2[m]+b2) @ W3 + b3); logits = h3 @ Wc + bc; softmax; pred
__global__ __launch_bounds__(256) void k_l3cls(const float* __restrict__ h2,
                                               const float* __restrict__ b2,
                                               const float* __restrict__ W3,
                                               const float* __restrict__ b3,
                                               const float* __restrict__ Wc,
                                               const float* __restrict__ bc,
                                               float* __restrict__ out) {
    int m = blockIdx.x;
    int t = threadIdx.x;
    int n = t & 31, kg = t >> 5;  // 8 k-groups of 128
    float acc = 0.f;
    const float* hrow = h2 + (size_t)m * 1024;
    for (int k = kg * 128; k < kg * 128 + 128; k++) {
        float a = fmaxf(hrow[k] + b2[k], 0.f);
        acc = fmaf(a, W3[(size_t)k * 32 + n], acc);
    }
    __shared__ float red[256];
    __shared__ float h3[32];
    red[t] = acc;
    __syncthreads();
    if (t < 32) {
        float s = 0.f;
        for (int g = 0; g < 8; g++) s += red[t + 32 * g];
        h3[t] = fmaxf(s + b3[t], 0.f);
    }
    __syncthreads();
    if (t == 0) {
        float l0 = bc[0], l1 = bc[1];
        for (int d = 0; d < 32; d++) {
            l0 = fmaf(h3[d], Wc[d * 2 + 0], l0);
            l1 = fmaf(h3[d], Wc[d * 2 + 1], l1);
        }
        float mx = fmaxf(l0, l1);
        float e0 = expf(l0 - mx), e1 = expf(l1 - mx);
        float inv = 1.f / (e0 + e1);
        out[m * 2 + 0] = e0 * inv;
        out[m * 2 + 1] = e1 * inv;
        out[200 + m] = (l1 > l0) ? 1.f : 0.f;
    }
}

extern "C" void kernel_launch(void* const* d_in, const int* in_sizes, int n_in,
                              void* d_out, int out_size, void* d_ws, size_t ws_size,
                              hipStream_t stream) {
    const float* feat_map = (const float*)d_in[0];
    const int* sp = (const int*)d_in[1];
    const int* y = (const int*)d_in[2];
    const float* W1 = (const float*)d_in[3];
    const float* b1 = (const float*)d_in[4];
    const float* W2 = (const float*)d_in[5];
    const float* b2 = (const float*)d_in[6];
    const float* W3 = (const float*)d_in[7];
    const float* b3 = (const float*)d_in[8];
    const float* Wc = (const float*)d_in[9];
    const float* bc = (const float*)d_in[10];
    float* out = (float*)d_out;
    float* ws = (float*)d_ws;

    float* featT = ws + OFF_FEATT;
    float* cnt = ws + OFF_CNT;
    float* lcnt = ws + OFF_LCNT;
    float* normsq = ws + OFF_NORMSQ;
    int* labels = (int*)(ws + OFF_LABELS);
    float* rnorm = ws + OFF_RNORM;
    float* h1 = ws + OFF_H1;
    float* h2 = ws + OFF_H2;

    hipLaunchKernelGGL(k_zero, dim3(800), dim3(256), 0, stream, (float4*)ws, WS_FLOATS / 4);
    hipLaunchKernelGGL(k_meta, dim3(64), dim3(256), 0, stream, sp, y, cnt, lcnt);
    hipLaunchKernelGGL(k_segsum, dim3(C_DIM), dim3(256), 0, stream, feat_map, sp, cnt, featT, normsq);
    hipLaunchKernelGGL(k_labels, dim3(1), dim3(128), 0, stream, cnt, lcnt, normsq, labels, rnorm);
    hipLaunchKernelGGL(k_prop, dim3(NSEG), dim3(128), 0, stream, featT, labels, rnorm, out);
    // layer1: h1 = featT^T @ W1   (M=128 pad, K=4224, N=1024), ksplit=12, Kt=352
    hipLaunchKernelGGL(k_gemm, dim3(16, 2, 12), dim3(256), 0, stream,
                       featT, FEATT_LD, 1, (const float*)nullptr, W1, 1024, h1, 1024, 352);
    // layer2: h2 = relu(h1+b1) @ W2  (K=1024, N=1024), ksplit=8, Kt=128
    hipLaunchKernelGGL(k_gemm, dim3(16, 2, 8), dim3(256), 0, stream,
                       h1, 1024, 0, b1, W2, 1024, h2, 1024, 128);
    hipLaunchKernelGGL(k_l3cls, dim3(NSEG), dim3(256), 0, stream, h2, b2, W3, b3, Wc, bc, out);
}

// Round 6
// 1356.623 us; speedup vs baseline: 1.6161x; 1.6161x over previous
//
#include <hip/hip_runtime.h>
#include <math.h>

#define C_DIM 4224
#define HW_PIX 50176          // 224*224
#define NSEG 100

typedef __attribute__((ext_vector_type(8))) short bf16x8;
typedef __attribute__((ext_vector_type(4))) float f32x4;

// ---- workspace layout (float offsets) ----
// 685,184 floats = 2.74 MB (< round-1's proven-safe 3.21 MB). h2 aliases featT.
#define FEATT_LD    128
#define SZ_FEATT    (C_DIM * FEATT_LD)         // 540672
#define OFF_FEATT   0
#define OFF_CNT     (OFF_FEATT + SZ_FEATT)     // 540672
#define OFF_LCNT    (OFF_CNT + 128)            // 540800 (100*3 used)
#define OFF_LABELS  (OFF_LCNT + 384)           // 541184 (int storage)
#define OFF_AFF     (OFF_LABELS + 128)         // 541312 [100][128]
#define OFF_H1      (OFF_AFF + 12800)          // 554112 [128][1024]
#define WS_FLOATS   (OFF_H1 + 128 * 1024)      // 685184 floats = 2.74 MB

__device__ __forceinline__ ushort f2bf(float x) {
    unsigned u = __float_as_uint(x);
    return (ushort)((u + 0x7FFFu + ((u >> 16) & 1u)) >> 16);   // RNE
}
__device__ __forceinline__ float bf2f(ushort h) {
    return __uint_as_float(((unsigned)h) << 16);
}

__global__ __launch_bounds__(256) void k_zero(float4* p, int n4) {
    int i = blockIdx.x * blockDim.x + threadIdx.x;
    int stride = gridDim.x * blockDim.x;
    float4 z = make_float4(0.f, 0.f, 0.f, 0.f);
    for (; i < n4; i += stride) p[i] = z;
}

// cnt[s], lcnt[s][3] from sp, y
__global__ __launch_bounds__(256) void k_meta(const int* __restrict__ sp,
                                              const int* __restrict__ y,
                                              float* cnt, float* lcnt) {
    __shared__ float sc[NSEG];
    __shared__ float sl[NSEG * 3];
    int t = threadIdx.x;
    for (int i = t; i < NSEG; i += 256) sc[i] = 0.f;
    for (int i = t; i < NSEG * 3; i += 256) sl[i] = 0.f;
    __syncthreads();
    for (int p = blockIdx.x * 256 + t; p < HW_PIX; p += gridDim.x * 256) {
        int s = sp[p];
        int lab = y[p];
        atomicAdd(&sc[s], 1.f);
        atomicAdd(&sl[s * 3 + lab], 1.f);
    }
    __syncthreads();
    for (int i = t; i < NSEG; i += 256) if (sc[i] != 0.f) atomicAdd(&cnt[i], sc[i]);
    for (int i = t; i < NSEG * 3; i += 256) if (sl[i] != 0.f) atomicAdd(&lcnt[i], sl[i]);
}

// Segment-sum as one-hot MFMA GEMM: featT[c][s] += sum_{p in split, sp[p]==s} fm[c][p]
// A = fm (hi/lo bf16 split), B = onehot(sp) built in-registers (exact in bf16).
// Block: 32 channels x 128 segs, K-chunk 64 px, 4 waves. K-split blocks atomicAdd.
__global__ __launch_bounds__(256) void k_segmm(const float* __restrict__ fm,
                                               const int* __restrict__ sp,
                                               float* __restrict__ featT) {
    __shared__ ushort Ahi[32 * 64];
    __shared__ ushort Alo[32 * 64];
    __shared__ int spbuf[64];
    const int t = threadIdx.x;
    const int c0 = blockIdx.x * 32;
    const int split = blockIdx.y;
    const int row = t >> 3;            // 0..31
    const int kh = (t & 7) << 3;       // 0,8,..,56
    const size_t rowbase = (size_t)(c0 + row) * HW_PIX;
    const int kbase = split * 12544;

    f32x4 acc[4] = {{0.f,0.f,0.f,0.f},{0.f,0.f,0.f,0.f},{0.f,0.f,0.f,0.f},{0.f,0.f,0.f,0.f}};

    // prologue: prefetch chunk 0
    const float* gp = fm + rowbase + kbase + kh;
    float4 v0 = *(const float4*)gp;
    float4 v1 = *(const float4*)(gp + 4);
    int4 sreg = make_int4(0, 0, 0, 0);
    if (t < 16) sreg = *(const int4*)(sp + kbase + t * 4);

    const int l = t & 63;
    const int w = t >> 6;
    const int mt = w & 1;              // M-tile of this wave
    const int cb = (w >> 1) << 6;      // col base (0 or 64)
    const int lrow = mt * 16 + (l & 15);
    const int kg = (l >> 4) << 3;      // 0,8,16,24
    const unsigned wboff = ((unsigned)((row << 7) + (kh << 1))) ^ ((unsigned)(row & 7) << 4);
    const unsigned swzr = (unsigned)(lrow & 7) << 4;

#pragma unroll 1
    for (int ch = 0; ch < 196; ++ch) {
        // convert staged chunk to hi/lo bf16
        float xs[8] = {v0.x, v0.y, v0.z, v0.w, v1.x, v1.y, v1.z, v1.w};
        union { ushort u[8]; bf16x8 v; } ph, pl;
#pragma unroll
        for (int e = 0; e < 8; ++e) {
            ushort h = f2bf(xs[e]);
            ph.u[e] = h;
            pl.u[e] = f2bf(xs[e] - bf2f(h));
        }
        __syncthreads();                       // prior compute done reading LDS
        *(bf16x8*)((char*)Ahi + wboff) = ph.v;
        *(bf16x8*)((char*)Alo + wboff) = pl.v;
        if (t < 16) *(int4*)((char*)spbuf + (t << 4)) = sreg;
        __syncthreads();                       // tile ready
        // prefetch next chunk (hides HBM latency under MFMA phase)
        if (ch + 1 < 196) {
            const float* gn = fm + rowbase + kbase + (ch + 1) * 64 + kh;
            v0 = *(const float4*)gn;
            v1 = *(const float4*)(gn + 4);
            if (t < 16) sreg = *(const int4*)(sp + kbase + (ch + 1) * 64 + t * 4);
        }
        // compute: 2 k-steps of 32, 4 N-tiles, hi+lo MFMA
#pragma unroll
        for (int ks = 0; ks < 2; ++ks) {
            const int kb = (ks << 5) + kg;
            int4 sa = *(const int4*)((char*)spbuf + (kb << 2));
            int4 sb = *(const int4*)((char*)spbuf + (kb << 2) + 16);
            unsigned aoff = ((unsigned)((lrow << 7) + (kb << 1))) ^ swzr;
            bf16x8 ah = *(bf16x8*)((char*)Ahi + aoff);
            bf16x8 al = *(bf16x8*)((char*)Alo + aoff);
#pragma unroll
            for (int n = 0; n < 4; ++n) {
                const int col = cb + (n << 4) + (l & 15);
                union { unsigned u[4]; bf16x8 v; } bb;
                bb.u[0] = (sa.x == col ? 0x3F80u : 0u) | (sa.y == col ? 0x3F800000u : 0u);
                bb.u[1] = (sa.z == col ? 0x3F80u : 0u) | (sa.w == col ? 0x3F800000u : 0u);
                bb.u[2] = (sb.x == col ? 0x3F80u : 0u) | (sb.y == col ? 0x3F800000u : 0u);
                bb.u[3] = (sb.z == col ? 0x3F80u : 0u) | (sb.w == col ? 0x3F800000u : 0u);
                acc[n] = __builtin_amdgcn_mfma_f32_16x16x32_bf16(ah, bb.v, acc[n], 0, 0, 0);
                acc[n] = __builtin_amdgcn_mfma_f32_16x16x32_bf16(al, bb.v, acc[n], 0, 0, 0);
            }
        }
    }
    // epilogue: C-frag mapping col=lane&15, row=(lane>>4)*4+r  [m89 verified]
    // K-split blocks accumulate via global f32 atomics (order-variation ~1 ulp).
    float* pb = featT + ((size_t)(c0 + mt * 16 + ((l >> 4) << 2))) * FEATT_LD
                + cb + (l & 15);
#pragma unroll
    for (int n = 0; n < 4; ++n)
#pragma unroll
        for (int r = 0; r < 4; ++r)
            atomicAdd(&pb[(size_t)r * FEATT_LD + (n << 4)], acc[n][r]);
}

// featT[c][s] /= max(cnt[s],1)  (in place)
__global__ __launch_bounds__(256) void k_finalize(const float* __restrict__ cnt,
                                                  float* __restrict__ featT) {
    int i = blockIdx.x * 256 + threadIdx.x;   // < 540672
    int s = i & 127;
    featT[i] = featT[i] / fmaxf(cnt[s], 1.f);
}

__global__ __launch_bounds__(128) void k_labels(const float* cnt, const float* lcnt,
                                                int* labels) {
    int s = threadIdx.x;
    if (s < NSEG) {
        float l0 = lcnt[s * 3 + 0], l1 = lcnt[s * 3 + 1], l2 = lcnt[s * 3 + 2];
        int lab = 0;
        float best = l0;
        if (l1 > best) { best = l1; lab = 1; }
        if (l2 > best) { lab = 2; }
        float cn = cnt[s];
        int ovr = (l2 > floorf(cn * 0.5f)) ? 2 : ((l1 >= 1.f) ? 1 : 0);
        labels[s] = (lab == 0) ? ovr : lab;
    }
}

// aff partial dots: block (i, ksplit); lane j; atomicAdd into aff[i][j]
__global__ __launch_bounds__(128) void k_prop_part(const float* __restrict__ featT,
                                                   float* __restrict__ aff) {
    int i = blockIdx.x;
    int j = threadIdx.x;
    int kb = blockIdx.y * 528;
    const float* fa = featT + (size_t)kb * FEATT_LD;
    float a0 = 0.f, a1 = 0.f, a2 = 0.f, a3 = 0.f;
#pragma unroll 4
    for (int k = 0; k < 528; k += 4) {
        a0 = fmaf(fa[(size_t)(k + 0) * FEATT_LD + i], fa[(size_t)(k + 0) * FEATT_LD + j], a0);
        a1 = fmaf(fa[(size_t)(k + 1) * FEATT_LD + i], fa[(size_t)(k + 1) * FEATT_LD + j], a1);
        a2 = fmaf(fa[(size_t)(k + 2) * FEATT_LD + i], fa[(size_t)(k + 2) * FEATT_LD + j], a2);
        a3 = fmaf(fa[(size_t)(k + 3) * FEATT_LD + i], fa[(size_t)(k + 3) * FEATT_LD + j], a3);
    }
    atomicAdd(&aff[i * FEATT_LD + j], ((a0 + a1) + (a2 + a3)));
}

// finalize propagation: rnorm from aff diagonal; masked first-max argmax per row
__global__ __launch_bounds__(128) void k_prop_final(const float* __restrict__ aff,
                                                    const int* __restrict__ labels,
                                                    float* __restrict__ out) {
    __shared__ float rn[128];
    __shared__ int lab[128];
    int t = threadIdx.x;
    rn[t] = (t < NSEG) ? rsqrtf(aff[t * FEATT_LD + t]) : 0.f;
    lab[t] = (t < NSEG) ? labels[t] : 0;
    __syncthreads();
    if (t < NSEG) {
        float ri = rn[t];
        float best = -INFINITY;
        int bi = 0;
        for (int j = 0; j < NSEG; ++j) {
            if (lab[j] != 0) {
                float v = aff[t * FEATT_LD + j] * ri * rn[j];
                if (v > best) { best = v; bi = j; }
            }
        }
        int li = lab[t];
        int prop = (li == 0 && best >= 0.8f) ? lab[bi] : li;
        out[300 + t] = (float)prop;
    }
}

// C(128 x N) += op(A)(128 x K) @ B(K x N); op = optional relu(x + abias[k])
// transA=1: A is featT-style K-major with leading dim lda (element (m,k) at A[k*lda+m])
// grid: x = N/64, y = 2 (m tiles of 64), z = ksplit; Kt = K/ksplit (multiple of 32)
__global__ __launch_bounds__(256) void k_gemm(const float* __restrict__ A, int lda, int transA,
                                              const float* __restrict__ abias,
                                              const float* __restrict__ B, int ldb,
                                              float* __restrict__ Cout, int ldc, int Kt) {
    __shared__ float As[32][68];
    int t = threadIdx.x;
    int tx = t & 15, ty = t >> 4;
    int n0 = blockIdx.x * 64;
    int m0 = blockIdx.y * 64;
    int k0 = blockIdx.z * Kt;
    float acc[4][4] = {};
    for (int ks = 0; ks < Kt; ks += 32) {
        __syncthreads();
        if (transA) {
            for (int idx = t; idx < 512; idx += 256) {
                int kk = idx >> 4, mq = idx & 15;
                int gk = k0 + ks + kk;
                float4 v = *(const float4*)(A + (size_t)gk * lda + m0 + mq * 4);
                *(float4*)&As[kk][mq * 4] = v;
            }
        } else {
            for (int idx = t; idx < 512; idx += 256) {
                int m = idx >> 3, kq = idx & 7;
                int gk = k0 + ks + kq * 4;
                float4 v = *(const float4*)(A + (size_t)(m0 + m) * lda + gk);
                if (abias) {
                    float4 b = *(const float4*)(abias + gk);
                    v.x = fmaxf(v.x + b.x, 0.f);
                    v.y = fmaxf(v.y + b.y, 0.f);
                    v.z = fmaxf(v.z + b.z, 0.f);
                    v.w = fmaxf(v.w + b.w, 0.f);
                }
                As[kq * 4 + 0][m] = v.x;
                As[kq * 4 + 1][m] = v.y;
                As[kq * 4 + 2][m] = v.z;
                As[kq * 4 + 3][m] = v.w;
            }
        }
        __syncthreads();
        const float* Bp = B + (size_t)(k0 + ks) * ldb + n0 + (tx << 2);
#pragma unroll
        for (int kk = 0; kk < 32; kk++) {
            float4 w = *(const float4*)(Bp + (size_t)kk * ldb);
            float4 a = *(const float4*)&As[kk][ty << 2];
            float av[4] = {a.x, a.y, a.z, a.w};
            float wv[4] = {w.x, w.y, w.z, w.w};
#pragma unroll
            for (int i = 0; i < 4; i++)
#pragma unroll
                for (int j = 0; j < 4; j++)
                    acc[i][j] = fmaf(av[i], wv[j], acc[i][j]);
        }
    }
#pragma unroll
    for (int i = 0; i < 4; i++) {
        int m = m0 + (ty << 2) + i;
#pragma unroll
        for (int j = 0; j < 4; j++)
            atomicAdd(&Cout[(size_t)m * ldc + n0 + (tx << 2) + j], acc[i][j]);
    }
}

// block m: h3 = relu(relu(h2[m]+b2) @ W3 + b3); logits = h3 @ Wc + bc; softmax; pred
__global__ __launch_bounds__(256) void k_l3cls(const float* __restrict__ h2,
                                               const float* __restrict__ b2,
                                               const float* __restrict__ W3,
                                               const float* __restrict__ b3,
                                               const float* __restrict__ Wc,
                                               const float* __restrict__ bc,
                                               float* __restrict__ out) {
    int m = blockIdx.x;
    int t = threadIdx.x;
    int n = t & 31, kg = t >> 5;  // 8 k-groups of 128
    float acc = 0.f;
    const float* hrow = h2 + (size_t)m * 1024;
    for (int k = kg * 128; k < kg * 128 + 128; k++) {
        float a = fmaxf(hrow[k] + b2[k], 0.f);
        acc = fmaf(a, W3[(size_t)k * 32 + n], acc);
    }
    __shared__ float red[256];
    __shared__ float h3[32];
    red[t] = acc;
    __syncthreads();
    if (t < 32) {
        float s = 0.f;
        for (int g = 0; g < 8; g++) s += red[t + 32 * g];
        h3[t] = fmaxf(s + b3[t], 0.f);
    }
    __syncthreads();
    if (t == 0) {
        float l0 = bc[0], l1 = bc[1];
        for (int d = 0; d < 32; d++) {
            l0 = fmaf(h3[d], Wc[d * 2 + 0], l0);
            l1 = fmaf(h3[d], Wc[d * 2 + 1], l1);
        }
        float mx = fmaxf(l0, l1);
        float e0 = expf(l0 - mx), e1 = expf(l1 - mx);
        float inv = 1.f / (e0 + e1);
        out[m * 2 + 0] = e0 * inv;
        out[m * 2 + 1] = e1 * inv;
        out[200 + m] = (l1 > l0) ? 1.f : 0.f;
    }
}

extern "C" void kernel_launch(void* const* d_in, const int* in_sizes, int n_in,
                              void* d_out, int out_size, void* d_ws, size_t ws_size,
                              hipStream_t stream) {
    const float* feat_map = (const float*)d_in[0];
    const int* sp = (const int*)d_in[1];
    const int* y = (const int*)d_in[2];
    const float* W1 = (const float*)d_in[3];
    const float* b1 = (const float*)d_in[4];
    const float* W2 = (const float*)d_in[5];
    const float* b2 = (const float*)d_in[6];
    const float* W3 = (const float*)d_in[7];
    const float* b3 = (const float*)d_in[8];
    const float* Wc = (const float*)d_in[9];
    const float* bc = (const float*)d_in[10];
    float* out = (float*)d_out;
    float* ws = (float*)d_ws;

    float* featT = ws + OFF_FEATT;
    float* cnt = ws + OFF_CNT;
    float* lcnt = ws + OFF_LCNT;
    int* labels = (int*)(ws + OFF_LABELS);
    float* aff = ws + OFF_AFF;
    float* h1 = ws + OFF_H1;
    float* h2 = ws + OFF_FEATT;   // aliases featT (dead after gemm1)

    // zero entire used workspace (featT accum, cnt/lcnt, aff, h1)
    hipLaunchKernelGGL(k_zero, dim3(256), dim3(256), 0, stream,
                       (float4*)ws, WS_FLOATS / 4);
    hipLaunchKernelGGL(k_meta, dim3(64), dim3(256), 0, stream, sp, y, cnt, lcnt);
    hipLaunchKernelGGL(k_segmm, dim3(132, 4), dim3(256), 0, stream, feat_map, sp, featT);
    hipLaunchKernelGGL(k_finalize, dim3(2112), dim3(256), 0, stream, cnt, featT);
    hipLaunchKernelGGL(k_labels, dim3(1), dim3(128), 0, stream, cnt, lcnt, labels);
    hipLaunchKernelGGL(k_prop_part, dim3(100, 8), dim3(128), 0, stream, featT, aff);
    hipLaunchKernelGGL(k_prop_final, dim3(1), dim3(128), 0, stream, aff, labels, out);
    // layer1: h1 = featT^T @ W1   (M=128 pad, K=4224, N=1024), ksplit=12, Kt=352
    hipLaunchKernelGGL(k_gemm, dim3(16, 2, 12), dim3(256), 0, stream,
                       featT, FEATT_LD, 1, (const float*)nullptr, W1, 1024, h1, 1024, 352);
    // featT is dead now; zero its head region for h2 accumulation
    hipLaunchKernelGGL(k_zero, dim3(128), dim3(256), 0, stream,
                       (float4*)h2, (128 * 1024) / 4);
    // layer2: h2 = relu(h1+b1) @ W2  (K=1024, N=1024), ksplit=8, Kt=128
    hipLaunchKernelGGL(k_gemm, dim3(16, 2, 8), dim3(256), 0, stream,
                       h1, 1024, 0, b1, W2, 1024, h2, 1024, 128);
    hipLaunchKernelGGL(k_l3cls, dim3(NSEG), dim3(256), 0, stream, h2, b2, W3, b3, Wc, bc, out);
}